// Round 1
// baseline (128.785 us; speedup 1.0000x reference)
//
#include <hip/hip_runtime.h>

// ---------------------------------------------------------------------------
// Compile-time consequent membership table.
// zmf[r][k] = exp(-0.5*((z_k - c_r)/0.3)^2) with z_k = -0.3 + 0.01k,
// c_r = -0.3 + 0.4r  =>  zmf[r][k] = exp(-(k-40r)^2 / 1800).
// Computed constexpr in double: exp(-1/1800) via Taylor, then pow-by-squaring.
// ---------------------------------------------------------------------------
struct ZmfTab { float v[5][161]; };

static constexpr double cexp_taylor(double x) {
    double s = 1.0, t = 1.0;
    for (int i = 1; i < 40; ++i) { t = t * x / (double)i; s += t; }
    return s;
}
static constexpr double cpow_int(double b, long e) {
    double r = 1.0, p = b;
    while (e > 0) { if (e & 1) r *= p; p *= p; e >>= 1; }
    return r;
}
static constexpr ZmfTab make_zmf() {
    ZmfTab t{};
    const double c0 = cexp_taylor(-1.0 / 1800.0);   // exp(-1/1800)
    for (int r = 0; r < 5; ++r)
        for (int k = 0; k < 161; ++k) {
            long d = (long)(k - 40 * r);
            t.v[r][k] = (float)cpow_int(c0, d * d); // exp(-d^2/1800)
        }
    return t;
}
// __constant__ + wave-uniform index k  =>  scalar-cache s_load, not LDS/VMEM.
__constant__ ZmfTab ZMF = make_zmf();

__global__ __launch_bounds__(256) void fuzzy_coupling_kernel(
    const float* __restrict__ h,
    const int*   __restrict__ src,
    const int*   __restrict__ dst,
    float*       __restrict__ out,
    int E)
{
    int e = blockIdx.x * blockDim.x + threadIdx.x;
    if (e >= E) return;

    int si = src[e], di = dst[e];

    // h rows are 8 floats = 32 B, 16B-aligned: two float4 loads per row.
    const float4* h4 = (const float4*)h;
    float4 sa = h4[2 * si], sb = h4[2 * si + 1];
    float4 da = h4[2 * di], db = h4[2 * di + 1];

    float v0 = da.x - sa.x, v1 = da.y - sa.y, v2 = da.z - sa.z, v3 = da.w - sa.w;
    float v4 = db.x - sb.x, v5 = db.y - sb.y, v6 = db.z - sb.z, v7 = db.w - sb.w;

    float ss = fmaf(v0, v0, fmaf(v1, v1, fmaf(v2, v2, fmaf(v3, v3,
               fmaf(v4, v4, fmaf(v5, v5, fmaf(v6, v6, fmaf(v7, v7, 1e-12f))))))));

    float rn = rsqrtf(ss);
    float n  = ss * rn;                 // sqrt(ss)
    float x1 = fminf(n, 4.0f);          // clip to [0,4]; n >= 1e-6 > 0

    float c = v0 * rn;                  // v[0]/||v||
    c = fminf(fmaxf(c, -0.999999f), 0.999999f);

    // acos via Hastings polynomial: acos(x) = sqrt(1-x)*P(x), x in [0,1];
    // acos(-x) = pi - acos(x). Max err 6.7e-5 rad (0.004 deg vs sigma=45 deg).
    float ac = fabsf(c);
    float t  = sqrtf(1.0f - ac);
    float p  = fmaf(fmaf(fmaf(-0.0187293f, ac, 0.0742610f), ac, -0.2121144f),
                    ac, 1.5707288f);
    float r0 = t * p;
    float acosv = (c < 0.0f) ? (3.14159265358979f - r0) : r0;
    float u = acosv * 1.27323954473516f;   // * 4/pi  == x2_degrees / 45

    // Antecedent memberships: mu1[i] = exp(-0.5 (x1-i)^2), mu2[j] = exp(-0.5 (u-j)^2)
    float m1[5], m2[5];
#pragma unroll
    for (int i = 0; i < 5; ++i) {
        float d1 = x1 - (float)i;
        float d2 = u  - (float)i;
        m1[i] = __expf(-0.5f * d1 * d1);
        m2[i] = __expf(-0.5f * d2 * d2);
    }

    // Rule activations: max over OR-terms of min(mu1_i, mu2_j)
    float a0 = fmaxf(fmaxf(fminf(m1[2], m2[4]), fminf(m1[3], m2[4])),
               fmaxf(fminf(m1[3], m2[3]),
               fmaxf(fminf(m1[4], m2[3]), fminf(m1[4], m2[4]))));
    float a1 = fmaxf(fmaxf(fminf(m1[1], m2[4]), fminf(m1[2], m2[3])),
               fmaxf(fminf(m1[3], m2[2]), fminf(m1[4], m2[1])));
    float a2 = fmaxf(fmaxf(fminf(m1[0], m2[4]), fminf(m1[1], m2[3])),
               fmaxf(fminf(m1[2], m2[2]),
               fmaxf(fminf(m1[3], m2[1]), fminf(m1[4], m2[0]))));
    float a3 = fmaxf(fmaxf(fminf(m1[0], m2[3]), fminf(m1[1], m2[2])),
               fmaxf(fminf(m1[2], m2[1]), fminf(m1[3], m2[0])));
    float a4 = fmaxf(fmaxf(fmaxf(fminf(m1[0], m2[2]), fminf(m1[0], m2[1])),
               fmaxf(fminf(m1[0], m2[0]), fminf(m1[1], m2[1]))),
               fmaxf(fminf(m1[1], m2[0]), fminf(m1[2], m2[0])));

    // Mamdani aggregation + centroid over the 161-pt universe.
    // s0 = sum(agg), s1 = sum(agg * k); centroid = 0.01*s1/s0 - 0.3.
    float s0 = 0.0f, s1 = 0.0f;
#pragma unroll
    for (int k = 0; k < 161; ++k) {
        float m = fminf(a0, ZMF.v[0][k]);
        m = fmaxf(m, fminf(a1, ZMF.v[1][k]));
        m = fmaxf(m, fminf(a2, ZMF.v[2][k]));
        m = fmaxf(m, fminf(a3, ZMF.v[3][k]));
        m = fmaxf(m, fminf(a4, ZMF.v[4][k]));
        s0 += m;
        s1 = fmaf(m, (float)k, s1);
    }

    out[e] = fmaf(0.01f, s1 / s0, -0.3f);
}

extern "C" void kernel_launch(void* const* d_in, const int* in_sizes, int n_in,
                              void* d_out, int out_size, void* d_ws, size_t ws_size,
                              hipStream_t stream)
{
    const float* h   = (const float*)d_in[0];
    const int*   src = (const int*)d_in[1];
    const int*   dst = (const int*)d_in[2];
    // d_in[3] (etypes) is unused by the reference computation.
    float* out = (float*)d_out;

    int E = in_sizes[1];
    int block = 256;
    int grid  = (E + block - 1) / block;
    fuzzy_coupling_kernel<<<grid, block, 0, stream>>>(h, src, dst, out, E);
}

// Round 2
// 98.750 us; speedup vs baseline: 1.3041x; 1.3041x over previous
//
#include <hip/hip_runtime.h>

// ---------------------------------------------------------------------------
// Compile-time consequent membership table (constexpr => folded to inline
// literals in the unrolled aggregation loop; NO runtime loads).
// zmf[r][k] = exp(-0.5*((z_k - c_r)/0.3)^2), z_k = -0.3+0.01k, c_r = -0.3+0.4r
//           = exp(-(k-40r)^2 / 1800)
// ---------------------------------------------------------------------------
static constexpr double cexp_taylor(double x) {
    double s = 1.0, t = 1.0;
    for (int i = 1; i < 40; ++i) { t = t * x / (double)i; s += t; }
    return s;
}
static constexpr double cpow_int(double b, long e) {
    double r = 1.0, p = b;
    while (e > 0) { if (e & 1) r *= p; p *= p; e >>= 1; }
    return r;
}
struct ZmfTab { float v[5][161]; };
static constexpr ZmfTab make_zmf() {
    ZmfTab t{};
    const double c0 = cexp_taylor(-1.0 / 1800.0);   // exp(-1/1800)
    for (int r = 0; r < 5; ++r)
        for (int k = 0; k < 161; ++k) {
            long d = (long)(k - 40 * r);
            t.v[r][k] = (float)cpow_int(c0, d * d); // exp(-d^2/1800)
        }
    return t;
}
static constexpr ZmfTab ZMF = make_zmf();
// Terms with zmf < CUT are dead-coded at compile time. Worst-case centroid
// error from trimming < 1e-3 (tail mass ~7e-4 vs s0 >= ~5).
static constexpr float ZCUT = 1e-4f;

__global__ __launch_bounds__(256) void fuzzy_coupling_kernel(
    const float* __restrict__ h,
    const int*   __restrict__ src,
    const int*   __restrict__ dst,
    float*       __restrict__ out,
    int E)
{
    int e = blockIdx.x * blockDim.x + threadIdx.x;
    if (e >= E) return;

    int si = src[e], di = dst[e];

    // h rows are 8 floats = 32 B, 16B-aligned: two float4 loads per row.
    const float4* h4 = (const float4*)h;
    float4 sa = h4[2 * si], sb = h4[2 * si + 1];
    float4 da = h4[2 * di], db = h4[2 * di + 1];

    float v0 = da.x - sa.x, v1 = da.y - sa.y, v2 = da.z - sa.z, v3 = da.w - sa.w;
    float v4 = db.x - sb.x, v5 = db.y - sb.y, v6 = db.z - sb.z, v7 = db.w - sb.w;

    float ss = fmaf(v0, v0, fmaf(v1, v1, fmaf(v2, v2, fmaf(v3, v3,
               fmaf(v4, v4, fmaf(v5, v5, fmaf(v6, v6, fmaf(v7, v7, 1e-12f))))))));

    float rn = rsqrtf(ss);
    float n  = ss * rn;                 // sqrt(ss)
    float x1 = fminf(n, 4.0f);          // clip to [0,4]

    float c = v0 * rn;                  // v[0]/||v||
    c = fminf(fmaxf(c, -0.999999f), 0.999999f);

    // acos via Hastings polynomial: acos(x) = sqrt(1-x)*P(x), x in [0,1];
    // acos(-x) = pi - acos(x). Max err 6.7e-5 rad (0.004 deg; sigma = 45 deg).
    float ac = fabsf(c);
    float t  = sqrtf(1.0f - ac);
    float p  = fmaf(fmaf(fmaf(-0.0187293f, ac, 0.0742610f), ac, -0.2121144f),
                    ac, 1.5707288f);
    float r0 = t * p;
    float acosv = (c < 0.0f) ? (3.14159265358979f - r0) : r0;
    float u = acosv * 1.27323954473516f;   // * 4/pi == x2_degrees / 45

    // Antecedent memberships.
    float m1[5], m2[5];
#pragma unroll
    for (int i = 0; i < 5; ++i) {
        float d1 = x1 - (float)i;
        float d2 = u  - (float)i;
        m1[i] = __expf(-0.5f * d1 * d1);
        m2[i] = __expf(-0.5f * d2 * d2);
    }

    // Rule activations.
    float a0 = fmaxf(fmaxf(fminf(m1[2], m2[4]), fminf(m1[3], m2[4])),
               fmaxf(fminf(m1[3], m2[3]),
               fmaxf(fminf(m1[4], m2[3]), fminf(m1[4], m2[4]))));
    float a1 = fmaxf(fmaxf(fminf(m1[1], m2[4]), fminf(m1[2], m2[3])),
               fmaxf(fminf(m1[3], m2[2]), fminf(m1[4], m2[1])));
    float a2 = fmaxf(fmaxf(fminf(m1[0], m2[4]), fminf(m1[1], m2[3])),
               fmaxf(fminf(m1[2], m2[2]),
               fmaxf(fminf(m1[3], m2[1]), fminf(m1[4], m2[0]))));
    float a3 = fmaxf(fmaxf(fminf(m1[0], m2[3]), fminf(m1[1], m2[2])),
               fmaxf(fminf(m1[2], m2[1]), fminf(m1[3], m2[0])));
    float a4 = fmaxf(fmaxf(fmaxf(fminf(m1[0], m2[2]), fminf(m1[0], m2[1])),
               fmaxf(fminf(m1[0], m2[0]), fminf(m1[1], m2[1]))),
               fmaxf(fminf(m1[1], m2[0]), fminf(m1[2], m2[0])));
    float a[5] = {a0, a1, a2, a3, a4};

    // Mamdani aggregation + centroid. All ZMF.v[r][k] fold to inline literals
    // (constexpr table, fully unrolled k). Terms < ZCUT are compile-time dead.
    float s0 = 0.0f, s1 = 0.0f;
#pragma unroll
    for (int k = 0; k < 161; ++k) {
        float m = -1.0f;
        bool first = true;
#pragma unroll
        for (int r = 0; r < 5; ++r) {
            if (ZMF.v[r][k] >= ZCUT) {          // compile-time constant guard
                float tmin = fminf(a[r], ZMF.v[r][k]);
                m = first ? tmin : fmaxf(m, tmin);
                first = false;
            }
        }
        s0 += m;
        s1 = fmaf(m, (float)k, s1);
    }

    out[e] = fmaf(0.01f, s1 / s0, -0.3f);
}

extern "C" void kernel_launch(void* const* d_in, const int* in_sizes, int n_in,
                              void* d_out, int out_size, void* d_ws, size_t ws_size,
                              hipStream_t stream)
{
    const float* h   = (const float*)d_in[0];
    const int*   src = (const int*)d_in[1];
    const int*   dst = (const int*)d_in[2];
    // d_in[3] (etypes) is unused by the reference computation.
    float* out = (float*)d_out;

    int E = in_sizes[1];
    int block = 256;
    int grid  = (E + block - 1) / block;
    fuzzy_coupling_kernel<<<grid, block, 0, stream>>>(h, src, dst, out, E);
}

// Round 3
// 93.268 us; speedup vs baseline: 1.3808x; 1.0588x over previous
//
#include <hip/hip_runtime.h>

// ---------------------------------------------------------------------------
// Compile-time consequent membership table (constexpr => inline literals).
// zmf[r][k] = exp(-(k-40r)^2 / 1800)
// ---------------------------------------------------------------------------
static constexpr double cexp_taylor(double x) {
    double s = 1.0, t = 1.0;
    for (int i = 1; i < 40; ++i) { t = t * x / (double)i; s += t; }
    return s;
}
static constexpr double cpow_int(double b, long e) {
    double r = 1.0, p = b;
    while (e > 0) { if (e & 1) r *= p; p *= p; e >>= 1; }
    return r;
}
struct ZmfTab { float v[5][161]; };
static constexpr ZmfTab make_zmf() {
    ZmfTab t{};
    const double c0 = cexp_taylor(-1.0 / 1800.0);
    for (int r = 0; r < 5; ++r)
        for (int k = 0; k < 161; ++k) {
            long d = (long)(k - 40 * r);
            t.v[r][k] = (float)cpow_int(c0, d * d);
        }
    return t;
}
static constexpr ZmfTab ZMF = make_zmf();
static constexpr float ZCUT = 1e-4f;

// F(x1, u): full Mamdani inference + centroid for antecedent coordinates
// x1 in [0,4] (distance) and u = angle_deg/45 in [0,4].
__device__ __forceinline__ float fuzzy_F(float x1, float u)
{
    float m1[5], m2[5];
#pragma unroll
    for (int i = 0; i < 5; ++i) {
        float d1 = x1 - (float)i;
        float d2 = u  - (float)i;
        m1[i] = __expf(-0.5f * d1 * d1);
        m2[i] = __expf(-0.5f * d2 * d2);
    }

    float a0 = fmaxf(fmaxf(fminf(m1[2], m2[4]), fminf(m1[3], m2[4])),
               fmaxf(fminf(m1[3], m2[3]),
               fmaxf(fminf(m1[4], m2[3]), fminf(m1[4], m2[4]))));
    float a1 = fmaxf(fmaxf(fminf(m1[1], m2[4]), fminf(m1[2], m2[3])),
               fmaxf(fminf(m1[3], m2[2]), fminf(m1[4], m2[1])));
    float a2 = fmaxf(fmaxf(fminf(m1[0], m2[4]), fminf(m1[1], m2[3])),
               fmaxf(fminf(m1[2], m2[2]),
               fmaxf(fminf(m1[3], m2[1]), fminf(m1[4], m2[0]))));
    float a3 = fmaxf(fmaxf(fminf(m1[0], m2[3]), fminf(m1[1], m2[2])),
               fmaxf(fminf(m1[2], m2[1]), fminf(m1[3], m2[0])));
    float a4 = fmaxf(fmaxf(fmaxf(fminf(m1[0], m2[2]), fminf(m1[0], m2[1])),
               fmaxf(fminf(m1[0], m2[0]), fminf(m1[1], m2[1]))),
               fmaxf(fminf(m1[1], m2[0]), fminf(m1[2], m2[0])));
    float a[5] = {a0, a1, a2, a3, a4};

    float s0 = 0.0f, s1 = 0.0f;
#pragma unroll
    for (int k = 0; k < 161; ++k) {
        float m = -1.0f;
        bool first = true;
#pragma unroll
        for (int r = 0; r < 5; ++r) {
            if (ZMF.v[r][k] >= ZCUT) {          // compile-time constant guard
                float tmin = fminf(a[r], ZMF.v[r][k]);
                m = first ? tmin : fmaxf(m, tmin);
                first = false;
            }
        }
        s0 += m;
        s1 = fmaf(m, (float)k, s1);
    }
    return fmaf(0.01f, s1 / s0, -0.3f);
}

// ---------------------------------------------------------------------------
// Kernel A: build 512x512 bilinear table of F over [0,4]^2 into d_ws.
// tab[i1*512 + i2] = F(i1*h, i2*h), h = 4/511.
// ---------------------------------------------------------------------------
#define GRID_N 512

__global__ __launch_bounds__(256) void build_table_kernel(float* __restrict__ tab)
{
    int idx = blockIdx.x * blockDim.x + threadIdx.x;   // 0 .. 512*512-1
    int i1 = idx >> 9;
    int i2 = idx & 511;
    const float h = 4.0f / 511.0f;
    tab[idx] = fuzzy_F((float)i1 * h, (float)i2 * h);
}

// ---------------------------------------------------------------------------
// Kernel B: per-edge antecedent coords + bilinear table lookup.
// ---------------------------------------------------------------------------
__global__ __launch_bounds__(256) void fuzzy_coupling_kernel(
    const float* __restrict__ h,
    const int*   __restrict__ src,
    const int*   __restrict__ dst,
    const float* __restrict__ tab,
    float*       __restrict__ out,
    int E)
{
    int e = blockIdx.x * blockDim.x + threadIdx.x;
    if (e >= E) return;

    int si = src[e], di = dst[e];

    const float4* h4 = (const float4*)h;
    float4 sa = h4[2 * si], sb = h4[2 * si + 1];
    float4 da = h4[2 * di], db = h4[2 * di + 1];

    float v0 = da.x - sa.x, v1 = da.y - sa.y, v2 = da.z - sa.z, v3 = da.w - sa.w;
    float v4 = db.x - sb.x, v5 = db.y - sb.y, v6 = db.z - sb.z, v7 = db.w - sb.w;

    float ss = fmaf(v0, v0, fmaf(v1, v1, fmaf(v2, v2, fmaf(v3, v3,
               fmaf(v4, v4, fmaf(v5, v5, fmaf(v6, v6, fmaf(v7, v7, 1e-12f))))))));

    float rn = rsqrtf(ss);
    float n  = ss * rn;                 // sqrt(ss)
    float x1 = fminf(n, 4.0f);

    float c = v0 * rn;
    c = fminf(fmaxf(c, -0.999999f), 0.999999f);

    // Hastings acos: max err 6.7e-5 rad.
    float ac = fabsf(c);
    float t  = sqrtf(1.0f - ac);
    float p  = fmaf(fmaf(fmaf(-0.0187293f, ac, 0.0742610f), ac, -0.2121144f),
                    ac, 1.5707288f);
    float r0 = t * p;
    float acosv = (c < 0.0f) ? (3.14159265358979f - r0) : r0;
    float u = acosv * 1.27323954473516f;   // *4/pi == angle_deg / 45

    // Bilinear lookup in the 512x512 table over [0,4]^2.
    const float sc = 511.0f * 0.25f;
    float t1 = x1 * sc;
    float t2 = u  * sc;
    int i1 = min((int)t1, 510);
    int i2 = min((int)t2, 510);
    float f1 = t1 - (float)i1;
    float f2 = t2 - (float)i2;

    const float* r0p = tab + (i1 << 9) + i2;
    float v00 = r0p[0],   v01 = r0p[1];
    float v10 = r0p[512], v11 = r0p[513];

    float lo = fmaf(f2, v01 - v00, v00);
    float hi = fmaf(f2, v11 - v10, v10);
    out[e] = fmaf(f1, hi - lo, lo);
}

extern "C" void kernel_launch(void* const* d_in, const int* in_sizes, int n_in,
                              void* d_out, int out_size, void* d_ws, size_t ws_size,
                              hipStream_t stream)
{
    const float* h   = (const float*)d_in[0];
    const int*   src = (const int*)d_in[1];
    const int*   dst = (const int*)d_in[2];
    // d_in[3] (etypes) unused by the reference computation.
    float* out = (float*)d_out;
    float* tab = (float*)d_ws;          // 512*512*4 = 1 MB scratch

    // A: rebuild table every call (ws is re-poisoned before each timed call).
    build_table_kernel<<<(GRID_N * GRID_N) / 256, 256, 0, stream>>>(tab);

    // B: per-edge lookup.
    int E = in_sizes[1];
    int block = 256;
    int grid  = (E + block - 1) / block;
    fuzzy_coupling_kernel<<<grid, block, 0, stream>>>(h, src, dst, tab, out, E);
}

// Round 4
// 89.927 us; speedup vs baseline: 1.4321x; 1.0372x over previous
//
#include <hip/hip_runtime.h>

// ---------------------------------------------------------------------------
// Compile-time consequent membership table (constexpr => inline literals).
// zmf[r][k] = exp(-(k-40r)^2 / 1800)
// ---------------------------------------------------------------------------
static constexpr double cexp_taylor(double x) {
    double s = 1.0, t = 1.0;
    for (int i = 1; i < 40; ++i) { t = t * x / (double)i; s += t; }
    return s;
}
static constexpr double cpow_int(double b, long e) {
    double r = 1.0, p = b;
    while (e > 0) { if (e & 1) r *= p; p *= p; e >>= 1; }
    return r;
}
struct ZmfTab { float v[5][161]; };
static constexpr ZmfTab make_zmf() {
    ZmfTab t{};
    const double c0 = cexp_taylor(-1.0 / 1800.0);
    for (int r = 0; r < 5; ++r)
        for (int k = 0; k < 161; ++k) {
            long d = (long)(k - 40 * r);
            t.v[r][k] = (float)cpow_int(c0, d * d);
        }
    return t;
}
static constexpr ZmfTab ZMF = make_zmf();
static constexpr float ZCUT = 1e-4f;

// F(x1, u): full Mamdani inference + centroid, x1 in [0,4], u = angle/45 in [0,4].
__device__ __forceinline__ float fuzzy_F(float x1, float u)
{
    float m1[5], m2[5];
#pragma unroll
    for (int i = 0; i < 5; ++i) {
        float d1 = x1 - (float)i;
        float d2 = u  - (float)i;
        m1[i] = __expf(-0.5f * d1 * d1);
        m2[i] = __expf(-0.5f * d2 * d2);
    }

    float a0 = fmaxf(fmaxf(fminf(m1[2], m2[4]), fminf(m1[3], m2[4])),
               fmaxf(fminf(m1[3], m2[3]),
               fmaxf(fminf(m1[4], m2[3]), fminf(m1[4], m2[4]))));
    float a1 = fmaxf(fmaxf(fminf(m1[1], m2[4]), fminf(m1[2], m2[3])),
               fmaxf(fminf(m1[3], m2[2]), fminf(m1[4], m2[1])));
    float a2 = fmaxf(fmaxf(fminf(m1[0], m2[4]), fminf(m1[1], m2[3])),
               fmaxf(fminf(m1[2], m2[2]),
               fmaxf(fminf(m1[3], m2[1]), fminf(m1[4], m2[0]))));
    float a3 = fmaxf(fmaxf(fminf(m1[0], m2[3]), fminf(m1[1], m2[2])),
               fmaxf(fminf(m1[2], m2[1]), fminf(m1[3], m2[0])));
    float a4 = fmaxf(fmaxf(fmaxf(fminf(m1[0], m2[2]), fminf(m1[0], m2[1])),
               fmaxf(fminf(m1[0], m2[0]), fminf(m1[1], m2[1]))),
               fmaxf(fminf(m1[1], m2[0]), fminf(m1[2], m2[0])));
    float a[5] = {a0, a1, a2, a3, a4};

    float s0 = 0.0f, s1 = 0.0f;
#pragma unroll
    for (int k = 0; k < 161; ++k) {
        float m = -1.0f;
        bool first = true;
#pragma unroll
        for (int r = 0; r < 5; ++r) {
            if (ZMF.v[r][k] >= ZCUT) {          // compile-time constant guard
                float tmin = fminf(a[r], ZMF.v[r][k]);
                m = first ? tmin : fmaxf(m, tmin);
                first = false;
            }
        }
        s0 += m;
        s1 = fmaf(m, (float)k, s1);
    }
    return fmaf(0.01f, s1 / s0, -0.3f);
}

// ---------------------------------------------------------------------------
// Kernel A: 256x256 table of F over [0,4]^2, stored as horizontal float2
// pairs: tab2[i1*256 + i2] = ( F(i1,i2), F(i1,i2+1) )  (i2+1 clamped).
// One dwordx2 gather then serves both column neighbors in kernel B.
// ---------------------------------------------------------------------------
#define GN 256

__global__ __launch_bounds__(256) void build_table_kernel(float2* __restrict__ tab2)
{
    int idx = blockIdx.x * blockDim.x + threadIdx.x;   // 0 .. 65535
    int i1 = idx >> 8;
    int i2 = idx & 255;
    const float h = 4.0f / 255.0f;
    float f = fuzzy_F((float)i1 * h, (float)i2 * h);
    tab2[idx].x = f;
    if (i2 > 0)   tab2[idx - 1].y = f;
    if (i2 == 255) tab2[idx].y = f;     // clamp (unused: i2 index <= 254)
}

// ---------------------------------------------------------------------------
// Kernel B: per-edge antecedent coords + bilinear lookup; 2 edges / thread.
// ---------------------------------------------------------------------------
__device__ __forceinline__ float edge_eval(
    const float4* __restrict__ h4, const float2* __restrict__ tab2,
    int si, int di)
{
    float4 sa = h4[2 * si], sb = h4[2 * si + 1];
    float4 da = h4[2 * di], db = h4[2 * di + 1];

    float v0 = da.x - sa.x, v1 = da.y - sa.y, v2 = da.z - sa.z, v3 = da.w - sa.w;
    float v4 = db.x - sb.x, v5 = db.y - sb.y, v6 = db.z - sb.z, v7 = db.w - sb.w;

    float ss = fmaf(v0, v0, fmaf(v1, v1, fmaf(v2, v2, fmaf(v3, v3,
               fmaf(v4, v4, fmaf(v5, v5, fmaf(v6, v6, fmaf(v7, v7, 1e-12f))))))));

    float rn = rsqrtf(ss);
    float n  = ss * rn;                 // sqrt(ss)
    float x1 = fminf(n, 4.0f);

    float c = v0 * rn;
    c = fminf(fmaxf(c, -0.999999f), 0.999999f);

    // Hastings acos: max err 6.7e-5 rad (0.004 deg; sigma = 45 deg).
    float ac = fabsf(c);
    float t  = sqrtf(1.0f - ac);
    float p  = fmaf(fmaf(fmaf(-0.0187293f, ac, 0.0742610f), ac, -0.2121144f),
                    ac, 1.5707288f);
    float r0 = t * p;
    float acosv = (c < 0.0f) ? (3.14159265358979f - r0) : r0;
    float u = acosv * 1.27323954473516f;   // *4/pi == angle_deg / 45

    // Bilinear in the 256x256 pair-table over [0,4]^2: 2 dwordx2 gathers.
    const float sc = 255.0f * 0.25f;
    float t1 = x1 * sc;
    float t2 = u  * sc;
    int i1 = min((int)t1, 254);
    int i2 = min((int)t2, 254);
    float f1 = t1 - (float)i1;
    float f2 = t2 - (float)i2;

    float2 pl = tab2[(i1 << 8) + i2];         // (F[i1][i2],   F[i1][i2+1])
    float2 ph = tab2[(i1 << 8) + i2 + 256];   // (F[i1+1][i2], F[i1+1][i2+1])

    float lo = fmaf(f2, pl.y - pl.x, pl.x);
    float hi = fmaf(f2, ph.y - ph.x, ph.x);
    return fmaf(f1, hi - lo, lo);
}

__global__ __launch_bounds__(256) void fuzzy_coupling_kernel(
    const float* __restrict__ h,
    const int*   __restrict__ src,
    const int*   __restrict__ dst,
    const float2* __restrict__ tab2,
    float*       __restrict__ out,
    int E)
{
    int t = blockIdx.x * blockDim.x + threadIdx.x;
    int e0 = 2 * t;
    if (e0 >= E) return;

    const float4* h4 = (const float4*)h;

    if (e0 + 1 < E) {
        int2 sp = ((const int2*)src)[t];
        int2 dp = ((const int2*)dst)[t];
        float r0 = edge_eval(h4, tab2, sp.x, dp.x);
        float r1 = edge_eval(h4, tab2, sp.y, dp.y);
        ((float2*)out)[t] = make_float2(r0, r1);
    } else {
        out[e0] = edge_eval(h4, tab2, src[e0], dst[e0]);
    }
}

extern "C" void kernel_launch(void* const* d_in, const int* in_sizes, int n_in,
                              void* d_out, int out_size, void* d_ws, size_t ws_size,
                              hipStream_t stream)
{
    const float* h   = (const float*)d_in[0];
    const int*   src = (const int*)d_in[1];
    const int*   dst = (const int*)d_in[2];
    // d_in[3] (etypes) unused by the reference computation.
    float* out  = (float*)d_out;
    float2* tab = (float2*)d_ws;        // 256*256*8 = 512 KB scratch

    // A: rebuild table every call (ws is re-poisoned before each timed call).
    build_table_kernel<<<(GN * GN) / 256, 256, 0, stream>>>(tab);

    // B: per-edge lookup, 2 edges per thread.
    int E = in_sizes[1];
    int threads = (E + 1) / 2;
    int block = 256;
    int grid  = (threads + block - 1) / block;
    fuzzy_coupling_kernel<<<grid, block, 0, stream>>>(h, src, dst, tab, out, E);
}

// Round 5
// 84.873 us; speedup vs baseline: 1.5174x; 1.0595x over previous
//
#include <hip/hip_runtime.h>
#include <hip/hip_fp16.h>

// ---------------------------------------------------------------------------
// Compile-time consequent membership table (constexpr => inline literals).
// zmf[r][k] = exp(-(k-40r)^2 / 1800)
// ---------------------------------------------------------------------------
static constexpr double cexp_taylor(double x) {
    double s = 1.0, t = 1.0;
    for (int i = 1; i < 40; ++i) { t = t * x / (double)i; s += t; }
    return s;
}
static constexpr double cpow_int(double b, long e) {
    double r = 1.0, p = b;
    while (e > 0) { if (e & 1) r *= p; p *= p; e >>= 1; }
    return r;
}
struct ZmfTab { float v[5][161]; };
static constexpr ZmfTab make_zmf() {
    ZmfTab t{};
    const double c0 = cexp_taylor(-1.0 / 1800.0);
    for (int r = 0; r < 5; ++r)
        for (int k = 0; k < 161; ++k) {
            long d = (long)(k - 40 * r);
            t.v[r][k] = (float)cpow_int(c0, d * d);
        }
    return t;
}
static constexpr ZmfTab ZMF = make_zmf();
static constexpr float ZCUT = 1e-4f;

// F(x1, u): full Mamdani inference + centroid, x1 in [0,4], u = angle/45 in [0,4].
__device__ __forceinline__ float fuzzy_F(float x1, float u)
{
    float m1[5], m2[5];
#pragma unroll
    for (int i = 0; i < 5; ++i) {
        float d1 = x1 - (float)i;
        float d2 = u  - (float)i;
        m1[i] = __expf(-0.5f * d1 * d1);
        m2[i] = __expf(-0.5f * d2 * d2);
    }

    float a0 = fmaxf(fmaxf(fminf(m1[2], m2[4]), fminf(m1[3], m2[4])),
               fmaxf(fminf(m1[3], m2[3]),
               fmaxf(fminf(m1[4], m2[3]), fminf(m1[4], m2[4]))));
    float a1 = fmaxf(fmaxf(fminf(m1[1], m2[4]), fminf(m1[2], m2[3])),
               fmaxf(fminf(m1[3], m2[2]), fminf(m1[4], m2[1])));
    float a2 = fmaxf(fmaxf(fminf(m1[0], m2[4]), fminf(m1[1], m2[3])),
               fmaxf(fminf(m1[2], m2[2]),
               fmaxf(fminf(m1[3], m2[1]), fminf(m1[4], m2[0]))));
    float a3 = fmaxf(fmaxf(fminf(m1[0], m2[3]), fminf(m1[1], m2[2])),
               fmaxf(fminf(m1[2], m2[1]), fminf(m1[3], m2[0])));
    float a4 = fmaxf(fmaxf(fmaxf(fminf(m1[0], m2[2]), fminf(m1[0], m2[1])),
               fmaxf(fminf(m1[0], m2[0]), fminf(m1[1], m2[1]))),
               fmaxf(fminf(m1[1], m2[0]), fminf(m1[2], m2[0])));
    float a[5] = {a0, a1, a2, a3, a4};

    float s0 = 0.0f, s1 = 0.0f;
#pragma unroll
    for (int k = 0; k < 161; ++k) {
        float m = -1.0f;
        bool first = true;
#pragma unroll
        for (int r = 0; r < 5; ++r) {
            if (ZMF.v[r][k] >= ZCUT) {          // compile-time constant guard
                float tmin = fminf(a[r], ZMF.v[r][k]);
                m = first ? tmin : fmaxf(m, tmin);
                first = false;
            }
        }
        s0 += m;
        s1 = fmaf(m, (float)k, s1);
    }
    return fmaf(0.01f, s1 / s0, -0.3f);
}

// ---------------------------------------------------------------------------
// Kernel A: 256x256 PATCH table over [0,4]^2, one float4 per cell:
// tab4[i1][i2] = ( F(i1,i2), F(i1,i2+1), F(i1+1,i2), F(i1+1,i2+1) ).
// Each thread computes one F value and scatters it into the <=4 patches
// that reference it. One dwordx4 gather then serves a full bilinear patch.
// ---------------------------------------------------------------------------
#define GN 256

__global__ __launch_bounds__(256) void build_table_kernel(float* __restrict__ tabf)
{
    int idx = blockIdx.x * blockDim.x + threadIdx.x;   // 0 .. 65535
    int i1 = idx >> 8;
    int i2 = idx & 255;
    const float hstep = 4.0f / 255.0f;
    float f = fuzzy_F((float)i1 * hstep, (float)i2 * hstep);

    tabf[4 * idx + 0] = f;                                  // patch(i1,i2).x
    if (i2 > 0)           tabf[4 * (idx - 1)   + 1] = f;    // patch(i1,i2-1).y
    if (i1 > 0)           tabf[4 * (idx - GN)  + 2] = f;    // patch(i1-1,i2).z
    if (i1 > 0 && i2 > 0) tabf[4 * (idx - GN - 1) + 3] = f; // patch(i1-1,i2-1).w
}

// ---------------------------------------------------------------------------
// Kernel B: pack h rows (8 x f32 = 32 B) into fp16 rows (16 B => ONE dwordx4
// gather per row in kernel C, and 4 rows per 64 B L2 line).
// ---------------------------------------------------------------------------
__global__ __launch_bounds__(256) void pack_h_kernel(
    const float4* __restrict__ h4, __half2* __restrict__ hp, int N)
{
    int r = blockIdx.x * blockDim.x + threadIdx.x;
    if (r >= N) return;
    float4 a = h4[2 * r], b = h4[2 * r + 1];
    __half2* o = hp + 4 * r;
    o[0] = __floats2half2_rn(a.x, a.y);
    o[1] = __floats2half2_rn(a.z, a.w);
    o[2] = __floats2half2_rn(b.x, b.y);
    o[3] = __floats2half2_rn(b.z, b.w);
}

// ---------------------------------------------------------------------------
// Kernel C: per-edge antecedent coords + one-patch bilinear lookup.
// 3 scattered gathers per edge: 2 fp16 h-rows + 1 table patch.
// ---------------------------------------------------------------------------
struct H8 { __half2 p0, p1, p2, p3; };   // one packed 16 B row

__device__ __forceinline__ float edge_eval(
    const H8* __restrict__ hp, const float4* __restrict__ tab4,
    int si, int di)
{
    H8 s = hp[si];
    H8 d = hp[di];

    // packed fp16 subtract, then cvt to f32 (err <= ~2e-3 per comp).
    float2 d0 = __half22float2(__hsub2(d.p0, s.p0));
    float2 d1 = __half22float2(__hsub2(d.p1, s.p1));
    float2 d2 = __half22float2(__hsub2(d.p2, s.p2));
    float2 d3 = __half22float2(__hsub2(d.p3, s.p3));

    float ss = fmaf(d0.x, d0.x, fmaf(d0.y, d0.y, fmaf(d1.x, d1.x, fmaf(d1.y, d1.y,
               fmaf(d2.x, d2.x, fmaf(d2.y, d2.y, fmaf(d3.x, d3.x,
               fmaf(d3.y, d3.y, 1e-12f))))))));

    float rn = rsqrtf(ss);
    float n  = ss * rn;                 // sqrt(ss)
    float x1 = fminf(n, 4.0f);

    float c = d0.x * rn;
    c = fminf(fmaxf(c, -0.999999f), 0.999999f);

    // Hastings acos: max err 6.7e-5 rad (0.004 deg; sigma = 45 deg).
    float ac = fabsf(c);
    float t  = sqrtf(1.0f - ac);
    float p  = fmaf(fmaf(fmaf(-0.0187293f, ac, 0.0742610f), ac, -0.2121144f),
                    ac, 1.5707288f);
    float r0 = t * p;
    float acosv = (c < 0.0f) ? (3.14159265358979f - r0) : r0;
    float u = acosv * 1.27323954473516f;   // *4/pi == angle_deg / 45

    // One float4 patch gather + bilinear.
    const float sc = 255.0f * 0.25f;
    float t1 = x1 * sc;
    float t2 = u  * sc;
    int i1 = min((int)t1, 254);
    int i2 = min((int)t2, 254);
    float f1 = t1 - (float)i1;
    float f2 = t2 - (float)i2;

    float4 patch = tab4[(i1 << 8) + i2];  // (v00, v01, v10, v11)
    float lo = fmaf(f2, patch.y - patch.x, patch.x);
    float hi = fmaf(f2, patch.w - patch.z, patch.z);
    return fmaf(f1, hi - lo, lo);
}

__global__ __launch_bounds__(256) void fuzzy_coupling_kernel(
    const H8*    __restrict__ hp,
    const int*   __restrict__ src,
    const int*   __restrict__ dst,
    const float4* __restrict__ tab4,
    float*       __restrict__ out,
    int E)
{
    int t = blockIdx.x * blockDim.x + threadIdx.x;
    int e0 = 2 * t;
    if (e0 >= E) return;

    if (e0 + 1 < E) {
        int2 sp = ((const int2*)src)[t];
        int2 dp = ((const int2*)dst)[t];
        float r0 = edge_eval(hp, tab4, sp.x, dp.x);
        float r1 = edge_eval(hp, tab4, sp.y, dp.y);
        ((float2*)out)[t] = make_float2(r0, r1);
    } else {
        out[e0] = edge_eval(hp, tab4, src[e0], dst[e0]);
    }
}

extern "C" void kernel_launch(void* const* d_in, const int* in_sizes, int n_in,
                              void* d_out, int out_size, void* d_ws, size_t ws_size,
                              hipStream_t stream)
{
    const float* h   = (const float*)d_in[0];
    const int*   src = (const int*)d_in[1];
    const int*   dst = (const int*)d_in[2];
    // d_in[3] (etypes) unused by the reference computation.
    float* out = (float*)d_out;

    // ws layout: [0, 1 MB) float4 patch table; [1 MB, 1 MB + 16*N) fp16 rows.
    float*   tabf = (float*)d_ws;
    float4*  tab4 = (float4*)d_ws;
    __half2* hp   = (__half2*)((char*)d_ws + (size_t)GN * GN * 16);

    int N = in_sizes[0] / 8;
    int E = in_sizes[1];

    // A: rebuild patch table (ws re-poisoned before every timed call).
    build_table_kernel<<<(GN * GN) / 256, 256, 0, stream>>>(tabf);
    // B: pack h rows to fp16.
    pack_h_kernel<<<(N + 255) / 256, 256, 0, stream>>>((const float4*)h, hp, N);

    // C: per-edge lookup, 2 edges per thread.
    int threads = (E + 1) / 2;
    int grid = (threads + 255) / 256;
    fuzzy_coupling_kernel<<<grid, 256, 0, stream>>>(
        (const H8*)hp, src, dst, tab4, out, E);
}

// Round 6
// 80.596 us; speedup vs baseline: 1.5979x; 1.0531x over previous
//
#include <hip/hip_runtime.h>
#include <hip/hip_fp16.h>

// ---------------------------------------------------------------------------
// Compile-time consequent membership table (constexpr => inline literals).
// zmf[r][k] = exp(-(k-40r)^2 / 1800)
// ---------------------------------------------------------------------------
static constexpr double cexp_taylor(double x) {
    double s = 1.0, t = 1.0;
    for (int i = 1; i < 40; ++i) { t = t * x / (double)i; s += t; }
    return s;
}
static constexpr double cpow_int(double b, long e) {
    double r = 1.0, p = b;
    while (e > 0) { if (e & 1) r *= p; p *= p; e >>= 1; }
    return r;
}
struct ZmfTab { float v[5][161]; };
static constexpr ZmfTab make_zmf() {
    ZmfTab t{};
    const double c0 = cexp_taylor(-1.0 / 1800.0);
    for (int r = 0; r < 5; ++r)
        for (int k = 0; k < 161; ++k) {
            long d = (long)(k - 40 * r);
            t.v[r][k] = (float)cpow_int(c0, d * d);
        }
    return t;
}
static constexpr ZmfTab ZMF = make_zmf();
static constexpr float ZCUT = 1e-4f;

// F(x1, u): full Mamdani inference + centroid, x1 in [0,4], u = angle/45 in [0,4].
__device__ __forceinline__ float fuzzy_F(float x1, float u)
{
    float m1[5], m2[5];
#pragma unroll
    for (int i = 0; i < 5; ++i) {
        float d1 = x1 - (float)i;
        float d2 = u  - (float)i;
        m1[i] = __expf(-0.5f * d1 * d1);
        m2[i] = __expf(-0.5f * d2 * d2);
    }

    float a0 = fmaxf(fmaxf(fminf(m1[2], m2[4]), fminf(m1[3], m2[4])),
               fmaxf(fminf(m1[3], m2[3]),
               fmaxf(fminf(m1[4], m2[3]), fminf(m1[4], m2[4]))));
    float a1 = fmaxf(fmaxf(fminf(m1[1], m2[4]), fminf(m1[2], m2[3])),
               fmaxf(fminf(m1[3], m2[2]), fminf(m1[4], m2[1])));
    float a2 = fmaxf(fmaxf(fminf(m1[0], m2[4]), fminf(m1[1], m2[3])),
               fmaxf(fminf(m1[2], m2[2]),
               fmaxf(fminf(m1[3], m2[1]), fminf(m1[4], m2[0]))));
    float a3 = fmaxf(fmaxf(fminf(m1[0], m2[3]), fminf(m1[1], m2[2])),
               fmaxf(fminf(m1[2], m2[1]), fminf(m1[3], m2[0])));
    float a4 = fmaxf(fmaxf(fmaxf(fminf(m1[0], m2[2]), fminf(m1[0], m2[1])),
               fmaxf(fminf(m1[0], m2[0]), fminf(m1[1], m2[1]))),
               fmaxf(fminf(m1[1], m2[0]), fminf(m1[2], m2[0])));
    float a[5] = {a0, a1, a2, a3, a4};

    float s0 = 0.0f, s1 = 0.0f;
#pragma unroll
    for (int k = 0; k < 161; ++k) {
        float m = -1.0f;
        bool first = true;
#pragma unroll
        for (int r = 0; r < 5; ++r) {
            if (ZMF.v[r][k] >= ZCUT) {          // compile-time constant guard
                float tmin = fminf(a[r], ZMF.v[r][k]);
                m = first ? tmin : fmaxf(m, tmin);
                first = false;
            }
        }
        s0 += m;
        s1 = fmaf(m, (float)k, s1);
    }
    return fmaf(0.01f, s1 / s0, -0.3f);
}

// ---------------------------------------------------------------------------
// Table geometry: PN x PN patches over [0,4]^2, value grid VN = PN+1 points,
// step 4/PN. Patch = 4 x fp16 (v00,v01,v10,v11) = 8 B. Whole table 51.2 KB
// -> LDS-resident in the main kernel (ds_read_b64 instead of TA gather).
// ---------------------------------------------------------------------------
#define PN 80
#define VN 81
#define TAB_U4 ((PN * PN) / 2)       // 3200 uint4 = 51200 B

struct H8 { __half2 p0, p1, p2, p3; };   // one packed 16 B h-row

// Fused kernel A+B: blocks [0, nA) build the fp16 patch table from 81x81
// F-evals; blocks [nA, ...) pack h rows (8 x f32 -> 8 x fp16 = 16 B).
__global__ __launch_bounds__(256) void build_pack_kernel(
    const float4* __restrict__ h4, __half* __restrict__ gtab,
    __half2* __restrict__ hp, int N, int nA)
{
    int b = blockIdx.x;
    if (b < nA) {
        int idx = b * 256 + threadIdx.x;
        if (idx >= VN * VN) return;
        int i = idx / VN;
        int j = idx - i * VN;
        const float hstep = 4.0f / (float)PN;    // 0.05
        __half f = __float2half_rn(fuzzy_F((float)i * hstep, (float)j * hstep));
        // scatter into the <=4 patches referencing value (i,j)
        if (i < PN && j < PN) gtab[4 * (i * PN + j) + 0]           = f; // v00
        if (i < PN && j > 0)  gtab[4 * (i * PN + j - 1) + 1]       = f; // v01
        if (i > 0 && j < PN)  gtab[4 * ((i - 1) * PN + j) + 2]     = f; // v10
        if (i > 0 && j > 0)   gtab[4 * ((i - 1) * PN + j - 1) + 3] = f; // v11
    } else {
        int r = (b - nA) * 256 + threadIdx.x;
        if (r >= N) return;
        float4 a = h4[2 * r], c = h4[2 * r + 1];
        __half2* o = hp + 4 * r;
        o[0] = __floats2half2_rn(a.x, a.y);
        o[1] = __floats2half2_rn(a.z, a.w);
        o[2] = __floats2half2_rn(c.x, c.y);
        o[3] = __floats2half2_rn(c.z, c.w);
    }
}

// Per-edge: 2 scattered h-row gathers (TA) + 1 LDS patch read (DS pipe).
__device__ __forceinline__ float edge_eval(
    const H8* __restrict__ hp, const uint2* __restrict__ stab,
    int si, int di)
{
    H8 s = hp[si];
    H8 d = hp[di];

    float2 d0 = __half22float2(__hsub2(d.p0, s.p0));
    float2 d1 = __half22float2(__hsub2(d.p1, s.p1));
    float2 d2 = __half22float2(__hsub2(d.p2, s.p2));
    float2 d3 = __half22float2(__hsub2(d.p3, s.p3));

    float ss = fmaf(d0.x, d0.x, fmaf(d0.y, d0.y, fmaf(d1.x, d1.x, fmaf(d1.y, d1.y,
               fmaf(d2.x, d2.x, fmaf(d2.y, d2.y, fmaf(d3.x, d3.x,
               fmaf(d3.y, d3.y, 1e-12f))))))));

    float rn = rsqrtf(ss);
    float n  = ss * rn;                 // sqrt(ss)
    float x1 = fminf(n, 4.0f);

    float c = d0.x * rn;
    c = fminf(fmaxf(c, -0.999999f), 0.999999f);

    // Hastings acos: max err 6.7e-5 rad.
    float ac = fabsf(c);
    float t  = sqrtf(1.0f - ac);
    float p  = fmaf(fmaf(fmaf(-0.0187293f, ac, 0.0742610f), ac, -0.2121144f),
                    ac, 1.5707288f);
    float r0 = t * p;
    float acosv = (c < 0.0f) ? (3.14159265358979f - r0) : r0;
    float u = acosv * 1.27323954473516f;   // *4/pi == angle_deg / 45

    const float sc = (float)PN * 0.25f;    // 20
    float t1 = x1 * sc;
    float t2 = u  * sc;
    int i1 = min((int)t1, PN - 1);
    int i2 = min((int)t2, PN - 1);
    float f1 = t1 - (float)i1;
    float f2 = t2 - (float)i2;

    uint2 pk = stab[i1 * PN + i2];
    float2 lo2 = __half22float2(__builtin_bit_cast(__half2, pk.x)); // v00,v01
    float2 hi2 = __half22float2(__builtin_bit_cast(__half2, pk.y)); // v10,v11
    float lo = fmaf(f2, lo2.y - lo2.x, lo2.x);
    float hi = fmaf(f2, hi2.y - hi2.x, hi2.x);
    return fmaf(f1, hi - lo, lo);
}

__global__ __launch_bounds__(512) void fuzzy_coupling_kernel(
    const H8*    __restrict__ hp,
    const int*   __restrict__ src,
    const int*   __restrict__ dst,
    const uint4* __restrict__ gtab4,
    float*       __restrict__ out,
    int E)
{
    __shared__ uint4 stab4[TAB_U4];
    // Stage the 51.2 KB patch table into LDS (coalesced 16 B loads).
    for (int k = threadIdx.x; k < TAB_U4; k += 512) stab4[k] = gtab4[k];
    __syncthreads();
    const uint2* stab = (const uint2*)stab4;

    int t = blockIdx.x * 512 + threadIdx.x;
    int e0 = 4 * t;
    if (e0 >= E) return;

    if (e0 + 3 < E) {
        int4 sp = ((const int4*)src)[t];
        int4 dp = ((const int4*)dst)[t];
        float r0 = edge_eval(hp, stab, sp.x, dp.x);
        float r1 = edge_eval(hp, stab, sp.y, dp.y);
        float r2 = edge_eval(hp, stab, sp.z, dp.z);
        float r3 = edge_eval(hp, stab, sp.w, dp.w);
        ((float4*)out)[t] = make_float4(r0, r1, r2, r3);
    } else {
        for (int e = e0; e < E; ++e)
            out[e] = edge_eval(hp, stab, src[e], dst[e]);
    }
}

extern "C" void kernel_launch(void* const* d_in, const int* in_sizes, int n_in,
                              void* d_out, int out_size, void* d_ws, size_t ws_size,
                              hipStream_t stream)
{
    const float* h   = (const float*)d_in[0];
    const int*   src = (const int*)d_in[1];
    const int*   dst = (const int*)d_in[2];
    // d_in[3] (etypes) unused by the reference computation.
    float* out = (float*)d_out;

    // ws layout: [0, 51.2 KB) fp16 patch table; [64 KB, 64 KB + 16*N) fp16 rows.
    __half*  gtab = (__half*)d_ws;
    __half2* hp   = (__half2*)((char*)d_ws + 65536);

    int N = in_sizes[0] / 8;
    int E = in_sizes[1];

    int nA = (VN * VN + 255) / 256;          // 26 table blocks
    int nB = (N + 255) / 256;                // pack blocks
    build_pack_kernel<<<nA + nB, 256, 0, stream>>>(
        (const float4*)h, gtab, hp, N, nA);

    int threads = (E + 3) / 4;
    int grid = (threads + 511) / 512;
    fuzzy_coupling_kernel<<<grid, 512, 0, stream>>>(
        (const H8*)hp, src, dst, (const uint4*)gtab, out, E);
}

// Round 8
// 78.751 us; speedup vs baseline: 1.6353x; 1.0234x over previous
//
#include <hip/hip_runtime.h>
#include <hip/hip_fp16.h>

// Native clang vector types: __builtin_nontemporal_* requires these
// (HIP_vector_type structs are rejected).
typedef int   vi4 __attribute__((ext_vector_type(4)));
typedef float vf4 __attribute__((ext_vector_type(4)));

// ---------------------------------------------------------------------------
// Compile-time consequent membership table (constexpr => inline literals).
// zmf[r][k] = exp(-(k-40r)^2 / 1800)
// ---------------------------------------------------------------------------
static constexpr double cexp_taylor(double x) {
    double s = 1.0, t = 1.0;
    for (int i = 1; i < 40; ++i) { t = t * x / (double)i; s += t; }
    return s;
}
static constexpr double cpow_int(double b, long e) {
    double r = 1.0, p = b;
    while (e > 0) { if (e & 1) r *= p; p *= p; e >>= 1; }
    return r;
}
struct ZmfTab { float v[5][161]; };
static constexpr ZmfTab make_zmf() {
    ZmfTab t{};
    const double c0 = cexp_taylor(-1.0 / 1800.0);
    for (int r = 0; r < 5; ++r)
        for (int k = 0; k < 161; ++k) {
            long d = (long)(k - 40 * r);
            t.v[r][k] = (float)cpow_int(c0, d * d);
        }
    return t;
}
static constexpr ZmfTab ZMF = make_zmf();
static constexpr float ZCUT = 1e-4f;

// F(x1, u): full Mamdani inference + centroid, x1 in [0,4], u = angle/45 in [0,4].
__device__ __forceinline__ float fuzzy_F(float x1, float u)
{
    float m1[5], m2[5];
#pragma unroll
    for (int i = 0; i < 5; ++i) {
        float d1 = x1 - (float)i;
        float d2 = u  - (float)i;
        m1[i] = __expf(-0.5f * d1 * d1);
        m2[i] = __expf(-0.5f * d2 * d2);
    }

    float a0 = fmaxf(fmaxf(fminf(m1[2], m2[4]), fminf(m1[3], m2[4])),
               fmaxf(fminf(m1[3], m2[3]),
               fmaxf(fminf(m1[4], m2[3]), fminf(m1[4], m2[4]))));
    float a1 = fmaxf(fmaxf(fminf(m1[1], m2[4]), fminf(m1[2], m2[3])),
               fmaxf(fminf(m1[3], m2[2]), fminf(m1[4], m2[1])));
    float a2 = fmaxf(fmaxf(fminf(m1[0], m2[4]), fminf(m1[1], m2[3])),
               fmaxf(fminf(m1[2], m2[2]),
               fmaxf(fminf(m1[3], m2[1]), fminf(m1[4], m2[0]))));
    float a3 = fmaxf(fmaxf(fminf(m1[0], m2[3]), fminf(m1[1], m2[2])),
               fmaxf(fminf(m1[2], m2[1]), fminf(m1[3], m2[0])));
    float a4 = fmaxf(fmaxf(fmaxf(fminf(m1[0], m2[2]), fminf(m1[0], m2[1])),
               fmaxf(fminf(m1[0], m2[0]), fminf(m1[1], m2[1]))),
               fmaxf(fminf(m1[1], m2[0]), fminf(m1[2], m2[0])));
    float a[5] = {a0, a1, a2, a3, a4};

    float s0 = 0.0f, s1 = 0.0f;
#pragma unroll
    for (int k = 0; k < 161; ++k) {
        float m = -1.0f;
        bool first = true;
#pragma unroll
        for (int r = 0; r < 5; ++r) {
            if (ZMF.v[r][k] >= ZCUT) {          // compile-time constant guard
                float tmin = fminf(a[r], ZMF.v[r][k]);
                m = first ? tmin : fmaxf(m, tmin);
                first = false;
            }
        }
        s0 += m;
        s1 = fmaf(m, (float)k, s1);
    }
    return fmaf(0.01f, s1 / s0, -0.3f);
}

// ---------------------------------------------------------------------------
// Table: PN x PN fp16 patches (v00,v01,v10,v11 = 8 B) over [0,4]^2.
// PN=70 -> 39.2 KB: 4 blocks/CU x 512 threads = 32 waves/CU (occupancy probe).
// ---------------------------------------------------------------------------
#define PN 70
#define VN 71
#define TAB_U4 ((PN * PN) / 2)       // 2450 uint4 = 39200 B

struct H8 { __half2 p0, p1, p2, p3; };   // one packed 16 B h-row

// Fused: blocks [0,nA) build the fp16 patch table (71x71 F-evals);
// blocks [nA,...) pack h rows (8 x f32 -> 16 B fp16).
__global__ __launch_bounds__(256) void build_pack_kernel(
    const float4* __restrict__ h4, __half* __restrict__ gtab,
    __half2* __restrict__ hp, int N, int nA)
{
    int b = blockIdx.x;
    if (b < nA) {
        int idx = b * 256 + threadIdx.x;
        if (idx >= VN * VN) return;
        int i = idx / VN;
        int j = idx - i * VN;
        const float hstep = 4.0f / (float)PN;
        __half f = __float2half_rn(fuzzy_F((float)i * hstep, (float)j * hstep));
        if (i < PN && j < PN) gtab[4 * (i * PN + j) + 0]           = f; // v00
        if (i < PN && j > 0)  gtab[4 * (i * PN + j - 1) + 1]       = f; // v01
        if (i > 0 && j < PN)  gtab[4 * ((i - 1) * PN + j) + 2]     = f; // v10
        if (i > 0 && j > 0)   gtab[4 * ((i - 1) * PN + j - 1) + 3] = f; // v11
    } else {
        int r = (b - nA) * 256 + threadIdx.x;
        if (r >= N) return;
        float4 a = h4[2 * r], c = h4[2 * r + 1];
        __half2* o = hp + 4 * r;
        o[0] = __floats2half2_rn(a.x, a.y);
        o[1] = __floats2half2_rn(a.z, a.w);
        o[2] = __floats2half2_rn(c.x, c.y);
        o[3] = __floats2half2_rn(c.z, c.w);
    }
}

// Per-edge: 2 scattered h-row gathers (TA) + 1 LDS patch read (DS pipe).
__device__ __forceinline__ float edge_eval(
    const H8* __restrict__ hp, const uint2* __restrict__ stab,
    int si, int di)
{
    H8 s = hp[si];
    H8 d = hp[di];

    float2 d0 = __half22float2(__hsub2(d.p0, s.p0));
    float2 d1 = __half22float2(__hsub2(d.p1, s.p1));
    float2 d2 = __half22float2(__hsub2(d.p2, s.p2));
    float2 d3 = __half22float2(__hsub2(d.p3, s.p3));

    float ss = fmaf(d0.x, d0.x, fmaf(d0.y, d0.y, fmaf(d1.x, d1.x, fmaf(d1.y, d1.y,
               fmaf(d2.x, d2.x, fmaf(d2.y, d2.y, fmaf(d3.x, d3.x,
               fmaf(d3.y, d3.y, 1e-12f))))))));

    float rn = rsqrtf(ss);
    float n  = ss * rn;                 // sqrt(ss)
    float x1 = fminf(n, 4.0f);

    float c = d0.x * rn;
    c = fminf(fmaxf(c, -0.999999f), 0.999999f);

    // Hastings acos: max err 6.7e-5 rad.
    float ac = fabsf(c);
    float t  = sqrtf(1.0f - ac);
    float p  = fmaf(fmaf(fmaf(-0.0187293f, ac, 0.0742610f), ac, -0.2121144f),
                    ac, 1.5707288f);
    float r0 = t * p;
    float acosv = (c < 0.0f) ? (3.14159265358979f - r0) : r0;
    float u = acosv * 1.27323954473516f;   // *4/pi == angle_deg / 45

    const float sc = (float)PN * 0.25f;    // 17.5
    float t1 = x1 * sc;
    float t2 = u  * sc;
    int i1 = min((int)t1, PN - 1);
    int i2 = min((int)t2, PN - 1);
    float f1 = t1 - (float)i1;
    float f2 = t2 - (float)i2;

    uint2 pk = stab[i1 * PN + i2];
    float2 lo2 = __half22float2(__builtin_bit_cast(__half2, pk.x)); // v00,v01
    float2 hi2 = __half22float2(__builtin_bit_cast(__half2, pk.y)); // v10,v11
    float lo = fmaf(f2, lo2.y - lo2.x, lo2.x);
    float hi = fmaf(f2, hi2.y - hi2.x, hi2.x);
    return fmaf(f1, hi - lo, lo);
}

__global__ __launch_bounds__(512, 8) void fuzzy_coupling_kernel(
    const H8*    __restrict__ hp,
    const int*   __restrict__ src,
    const int*   __restrict__ dst,
    const uint4* __restrict__ gtab4,
    float*       __restrict__ out,
    int E)
{
    __shared__ uint4 stab4[TAB_U4];
    for (int k = threadIdx.x; k < TAB_U4; k += 512) stab4[k] = gtab4[k];
    __syncthreads();
    const uint2* stab = (const uint2*)stab4;

    int t = blockIdx.x * 512 + threadIdx.x;
    int e0 = 4 * t;
    if (e0 >= E) return;

    if (e0 + 3 < E) {
        // Non-temporal on streaming index loads / output store: keep the
        // 12 MB stream out of L1 so h-rows keep their L1 residency.
        vi4 sp = __builtin_nontemporal_load((const vi4*)src + t);
        vi4 dp = __builtin_nontemporal_load((const vi4*)dst + t);
        float r0 = edge_eval(hp, stab, sp.x, dp.x);
        float r1 = edge_eval(hp, stab, sp.y, dp.y);
        float r2 = edge_eval(hp, stab, sp.z, dp.z);
        float r3 = edge_eval(hp, stab, sp.w, dp.w);
        vf4 res; res.x = r0; res.y = r1; res.z = r2; res.w = r3;
        __builtin_nontemporal_store(res, (vf4*)out + t);
    } else {
        for (int e = e0; e < E; ++e)
            out[e] = edge_eval(hp, stab, src[e], dst[e]);
    }
}

extern "C" void kernel_launch(void* const* d_in, const int* in_sizes, int n_in,
                              void* d_out, int out_size, void* d_ws, size_t ws_size,
                              hipStream_t stream)
{
    const float* h   = (const float*)d_in[0];
    const int*   src = (const int*)d_in[1];
    const int*   dst = (const int*)d_in[2];
    // d_in[3] (etypes) unused by the reference computation.
    float* out = (float*)d_out;

    // ws layout: [0, 39.2 KB) fp16 patch table; [64 KB, 64 KB + 16*N) fp16 rows.
    __half*  gtab = (__half*)d_ws;
    __half2* hp   = (__half2*)((char*)d_ws + 65536);

    int N = in_sizes[0] / 8;
    int E = in_sizes[1];

    int nA = (VN * VN + 255) / 256;          // 20 table blocks
    int nB = (N + 255) / 256;                // pack blocks
    build_pack_kernel<<<nA + nB, 256, 0, stream>>>(
        (const float4*)h, gtab, hp, N, nA);

    int threads = (E + 3) / 4;
    int grid = (threads + 511) / 512;
    fuzzy_coupling_kernel<<<grid, 512, 0, stream>>>(
        (const H8*)hp, src, dst, (const uint4*)gtab, out, E);
}